// Round 4
// baseline (312.998 us; speedup 1.0000x reference)
//
#include <hip/hip_runtime.h>
#include <cstdint>

#define SEQ     3120
#define SPAD    3200
#define DIM     1536
#define NQKV    4608
#define HEADS   12
#define HD      128
#define SPATIAL 390
#define EPSV    1e-5f
#define KVBLK   64
#define NTILES  49
#define NEGBIG  (-1e30f)
// 1/sqrt(128) * log2(e): attention scores computed in log2 domain
#define QSCALE  (0.08838834764831845f * 1.4426950408889634f)
#define THRL2   11.0f

typedef unsigned short u16;
typedef short s16x8 __attribute__((ext_vector_type(8)));
typedef float f32x4 __attribute__((ext_vector_type(4)));
typedef float f32x16 __attribute__((ext_vector_type(16)));

__device__ __forceinline__ u16 f2bf(float f) {
  union { float f; unsigned u; } v; v.f = f;
  unsigned r = v.u + 0x7FFFu + ((v.u >> 16) & 1u);
  return (u16)(r >> 16);
}
__device__ __forceinline__ float bf2f(u16 b) {
  union { unsigned u; float f; } v; v.u = ((unsigned)b) << 16;
  return v.f;
}
__device__ __forceinline__ unsigned cvtpk(float lo, float hi) {
  unsigned r;
  asm("v_cvt_pk_bf16_f32 %0, %1, %2" : "=v"(r) : "v"(lo), "v"(hi));
  return r;
}
// async global->LDS, 16B per lane. LDS dest = wave-uniform base + lane*16.
__device__ __forceinline__ void gload16(const void* g, const void* l) {
  __builtin_amdgcn_global_load_lds(
      (const __attribute__((address_space(1))) unsigned*)g,
      (__attribute__((address_space(3))) unsigned*)(uintptr_t)l,
      16, 0, 0);
}

// ---------------- 1. convert x fp32 -> bf16, pad rows [SEQ,SPAD) with 0 ----
__global__ __launch_bounds__(256) void k_convert_x(const float* __restrict__ x,
                                                   u16* __restrict__ xb) {
  const int i = (blockIdx.x * 256 + threadIdx.x) * 4;
  if (i >= SPAD * DIM) return;
  const int row = i / DIM;
  float4 v = make_float4(0.f, 0.f, 0.f, 0.f);
  if (row < SEQ) v = *(const float4*)(x + i);
  const unsigned lo = (unsigned)f2bf(v.x) | ((unsigned)f2bf(v.y) << 16);
  const unsigned hi = (unsigned)f2bf(v.z) | ((unsigned)f2bf(v.w) << 16);
  *(uint2*)(xb + i) = make_uint2(lo, hi);
}

// ---------------- 2. transpose+convert weights: Wt[n][k] = W[k][n] ---------
__global__ __launch_bounds__(256) void k_transpose_w(
    const float* __restrict__ Wq, const float* __restrict__ Wk,
    const float* __restrict__ Wv, const float* __restrict__ Wo,
    u16* __restrict__ WtAll, u16* __restrict__ WoT) {
  const int wsel = blockIdx.z;
  const float* W = (wsel == 0) ? Wq : (wsel == 1) ? Wk : (wsel == 2) ? Wv : Wo;
  __shared__ float t[32][33];
  const int k0 = blockIdx.x * 32, n0 = blockIdx.y * 32;
  const int c = threadIdx.x & 31, r8 = threadIdx.x >> 5;
#pragma unroll
  for (int rr = 0; rr < 32; rr += 8)
    t[r8 + rr][c] = W[(size_t)(k0 + r8 + rr) * DIM + n0 + c];
  __syncthreads();
  u16* Wt = (wsel < 3) ? (WtAll + (size_t)wsel * DIM * DIM) : WoT;
#pragma unroll
  for (int rr = 0; rr < 32; rr += 8)
    Wt[(size_t)(n0 + r8 + rr) * DIM + k0 + c] = f2bf(t[c][r8 + rr]);
}

// ---------------- 3. concat bq|bk|bv ---------------------------------------
__global__ void k_biascat(const float* __restrict__ bq, const float* __restrict__ bk,
                          const float* __restrict__ bv, float* __restrict__ bcat) {
  const int i = blockIdx.x * 256 + threadIdx.x;
  if (i >= NQKV) return;
  bcat[i] = (i < DIM) ? bq[i] : (i < 2 * DIM) ? bk[i - DIM] : bv[i - 2 * DIM];
}

// ---------------- 4/8. bf16 MFMA GEMM: C[m][n] = sum_k A[m][k]*Bt[n][k]+bias
template <int OUT_BF16>
__global__ __launch_bounds__(256) void k_gemm(const u16* __restrict__ A,
                                              const u16* __restrict__ Bt,
                                              const float* __restrict__ bias,
                                              void* __restrict__ Cout,
                                              int N, int K, int storeMmax) {
  __shared__ short As[4096];  // [128][32]
  __shared__ short Bs[4096];  // [128][32]
  const int tid = threadIdx.x;
  const int lane = tid & 63, wv = tid >> 6;
  const int l15 = lane & 15, g = lane >> 4;
  const int brow = blockIdx.y * 128, bcol = blockIdx.x * 128;
  const int wr = wv >> 1, wc = wv & 1;

  const f32x4 z4 = {0.f, 0.f, 0.f, 0.f};
  f32x4 acc[4][4];
#pragma unroll
  for (int m = 0; m < 4; ++m)
#pragma unroll
    for (int n = 0; n < 4; ++n) acc[m][n] = z4;

  const int srow = wv * 16 + (lane >> 2);
  const int skk = (lane & 3) * 8;
  const u16* Ab = A + (size_t)(brow + srow) * K + skk;
  const u16* Bb = Bt + (size_t)(bcol + srow) * K + skk;
  short* AsW = As + wv * 512;
  short* BsW = Bs + wv * 512;
  const size_t step64 = (size_t)64 * K;

  for (int k0 = 0; k0 < K; k0 += 32) {
    __syncthreads();
    gload16(Ab + k0, AsW);
    gload16(Ab + k0 + step64, AsW + 2048);
    gload16(Bb + k0, BsW);
    gload16(Bb + k0 + step64, BsW + 2048);
    __syncthreads();
    s16x8 a[4], b[4];
#pragma unroll
    for (int m = 0; m < 4; ++m)
      a[m] = *(const s16x8*)&As[(wr * 64 + m * 16 + l15) * 32 + g * 8];
#pragma unroll
    for (int n = 0; n < 4; ++n)
      b[n] = *(const s16x8*)&Bs[(wc * 64 + n * 16 + l15) * 32 + g * 8];
#pragma unroll
    for (int m = 0; m < 4; ++m)
#pragma unroll
      for (int n = 0; n < 4; ++n)
        acc[m][n] = __builtin_amdgcn_mfma_f32_16x16x32_bf16(a[m], b[n], acc[m][n], 0, 0, 0);
  }

#pragma unroll
  for (int m = 0; m < 4; ++m) {
#pragma unroll
    for (int n = 0; n < 4; ++n) {
      const int cc = bcol + wc * 64 + n * 16 + l15;
      const float bb = bias[cc];
#pragma unroll
      for (int i = 0; i < 4; ++i) {
        const int r = brow + wr * 64 + m * 16 + g * 4 + i;
        if (r < storeMmax) {
          const float v = acc[m][n][i] + bb;
          if (OUT_BF16) ((u16*)Cout)[(size_t)r * N + cc] = f2bf(v);
          else          ((float*)Cout)[(size_t)r * N + cc] = v;
        }
      }
    }
  }
}

// ---------------- 5. per-token: rmsnorm + rope + biases --------------------
__global__ __launch_bounds__(256) void k_post(
    const u16* __restrict__ Pqkv, const float* __restrict__ freqs,
    const float* __restrict__ gq, const float* __restrict__ gk,
    const float* __restrict__ qkfb, const float* __restrict__ vfb,
    const float* __restrict__ vsb,
    u16* __restrict__ Qf, u16* __restrict__ Kf, u16* __restrict__ Vf) {
  const int s = blockIdx.x;
  const int t = threadIdx.x;
  const int fidx = s / SPATIAL;
  const int sp = s - fidx * SPATIAL;
  __shared__ float cs[64], sn[64];
  __shared__ float red[8];
  if (t < 64) {
    const float a = freqs[s * 64 + t];
    cs[t] = __cosf(a);
    sn[t] = __sinf(a);
  }
  const u16* qrow = Pqkv + (size_t)s * NQKV;
  const u16* krow = qrow + DIM;
  const u16* vrow = qrow + 2 * DIM;
  float sq = 0.f, sk = 0.f;
  for (int i = t; i < DIM; i += 256) {
    const float a = bf2f(qrow[i]); sq += a * a;
    const float b = bf2f(krow[i]); sk += b * b;
  }
#pragma unroll
  for (int off = 1; off < 64; off <<= 1) {
    sq += __shfl_xor(sq, off);
    sk += __shfl_xor(sk, off);
  }
  const int lane = t & 63, wv = t >> 6;
  if (lane == 0) { red[wv] = sq; red[wv + 4] = sk; }
  __syncthreads();
  sq = red[0] + red[1] + red[2] + red[3];
  sk = red[4] + red[5] + red[6] + red[7];
  const float rq = rsqrtf(sq * (1.0f / DIM) + EPSV);
  const float rk = rsqrtf(sk * (1.0f / DIM) + EPSV);
  for (int p = t; p < 768; p += 256) {
    const int d = 2 * p;
    const int pin = p & 63;
    const float c = cs[pin], s_ = sn[pin];
    const float bq0 = qkfb[fidx * DIM + d], bq1 = qkfb[fidx * DIM + d + 1];
    float xr = bf2f(qrow[d]) * rq * gq[d];
    float xi = bf2f(qrow[d + 1]) * rq * gq[d + 1];
    const float q0 = (xr * c - xi * s_ + bq0) * QSCALE;
    const float q1 = (xr * s_ + xi * c + bq1) * QSCALE;
    *(unsigned*)&Qf[(size_t)s * DIM + d] = (unsigned)f2bf(q0) | ((unsigned)f2bf(q1) << 16);
    xr = bf2f(krow[d]) * rk * gk[d];
    xi = bf2f(krow[d + 1]) * rk * gk[d + 1];
    const float k0 = xr * c - xi * s_ + bq0;
    const float k1 = xr * s_ + xi * c + bq1;
    *(unsigned*)&Kf[(size_t)s * DIM + d] = (unsigned)f2bf(k0) | ((unsigned)f2bf(k1) << 16);
    const float v0 = bf2f(vrow[d]) + vfb[fidx * DIM + d] + vsb[(size_t)sp * DIM + d];
    const float v1 = bf2f(vrow[d + 1]) + vfb[fidx * DIM + d + 1] + vsb[(size_t)sp * DIM + d + 1];
    *(unsigned*)&Vf[(size_t)s * DIM + d] = (unsigned)f2bf(v0) | ((unsigned)f2bf(v1) << 16);
  }
}

// ---------------- 6. V transpose: Vf[s][1536] -> Vt[dglob][SPAD] -----------
__global__ __launch_bounds__(256) void k_transpose_v(const u16* __restrict__ Vf,
                                                     u16* __restrict__ Vt) {
  __shared__ u16 tile[64][65];
  const int s0 = blockIdx.x * 64, c0 = blockIdx.y * 64;
  const int c = threadIdx.x & 63, r4 = threadIdx.x >> 6;
#pragma unroll
  for (int rr = 0; rr < 64; rr += 4) {
    const int s = s0 + r4 + rr;
    tile[r4 + rr][c] = (s < SEQ) ? Vf[(size_t)s * DIM + c0 + c] : (u16)0;
  }
  __syncthreads();
#pragma unroll
  for (int rr = 0; rr < 64; rr += 4) {
    const int dglob = c0 + r4 + rr;
    Vt[(size_t)dglob * SPAD + s0 + c] = tile[c][r4 + rr];
  }
}

// ---------------- 7. flash attention, 32x32 MFMA, swapped QK^T, split-KV ---
// grid (20, 12, 2), 320 threads = 5 warps. z-half owns KV tiles [z*25, ...).
// Warp w owns q rows bx*160+w*32..+31; lane owns q-row l&31 (partner lane^32).
// Writes unnormalized partial O (bf16) + per-row (m, s) to workspace.
__global__ __launch_bounds__(320, 2) void k_attn(const u16* __restrict__ Qf,
                                                 const u16* __restrict__ Kf,
                                                 const u16* __restrict__ Vt,
                                                 u16* __restrict__ Opart,
                                                 float2* __restrict__ ms) {
  __shared__ short Ks[2][8192];  // [64 key][16 chunk][8]
  __shared__ short Vs[2][8192];  // [128 d][8 chunk][8]
  const int h = blockIdx.y;
  const int z = blockIdx.z;
  const int t0 = z * 25;
  const int nt = z ? (NTILES - 25) : 25;
  const int tid = threadIdx.x;
  const int lane = tid & 63, w = tid >> 6;     // w in 0..4
  const int l31 = lane & 31, hi = lane >> 5;
  const int qrow = blockIdx.x * 160 + w * 32 + l31;

  // Q B-frags: qb[s] = Q[qrow][16s + 8hi + j]
  s16x8 qb[8];
  {
    const u16* qp = Qf + (size_t)qrow * DIM + h * HD + hi * 8;
#pragma unroll
    for (int s = 0; s < 8; ++s) qb[s] = *(const s16x8*)(qp + s * 16);
  }

  f32x16 o[4];
#pragma unroll
  for (int d = 0; d < 4; ++d)
#pragma unroll
    for (int r = 0; r < 16; ++r) o[d][r] = 0.f;
  float m = NEGBIG, sl = 0.f;

  // staging pointers (warps 0..3 only)
  const u16* Kp[4];
  const u16* Vp[4];
  if (w < 4) {
#pragma unroll
    for (int it = 0; it < 4; ++it) {
      const int krow = w * 16 + it * 4 + (lane >> 4);
      const int kch = (lane & 15) ^ (it * 4 + (lane >> 4));
      Kp[it] = Kf + (size_t)krow * DIM + h * HD + kch * 8;
      const int vrow = w * 32 + it * 8 + (lane >> 3);
      const int vch = (lane & 7) ^ (lane >> 3);
      Vp[it] = Vt + (size_t)(h * HD + vrow) * SPAD + vch * 8;
    }
  }
  auto stage = [&](int T, int B) {
    const size_t kof = (size_t)T * KVBLK * DIM;
    const int vof = T * KVBLK;
#pragma unroll
    for (int it = 0; it < 4; ++it) {
      gload16(Kp[it] + kof, &Ks[B][(w * 16 + it * 4) * 128]);
      gload16(Vp[it] + vof, &Vs[B][(w * 32 + it * 8) * 64]);
    }
  };

  if (w < 4) {
    asm volatile("s_waitcnt vmcnt(0)" ::: "memory");
    stage(t0, 0);
  }

  for (int lt = 0; lt < nt; ++lt) {
    const int b = lt & 1;
    if (w < 4) {
      if (lt + 1 < nt) {
        stage(t0 + lt + 1, b ^ 1);
        asm volatile("s_waitcnt vmcnt(8)" ::: "memory");
      } else {
        asm volatile("s_waitcnt vmcnt(0)" ::: "memory");
      }
    }
    __builtin_amdgcn_s_barrier();
    __builtin_amdgcn_sched_barrier(0);

    // S^T = K Q  (D[key][q]: col q = l31, row key = (r&3)+8*(r>>2)+4hi)
    f32x16 st[2];
#pragma unroll
    for (int r = 0; r < 16; ++r) { st[0][r] = 0.f; st[1][r] = 0.f; }
    __builtin_amdgcn_s_setprio(1);
#pragma unroll
    for (int grp = 0; grp < 2; ++grp)
#pragma unroll
      for (int s = 0; s < 8; ++s) {
        const s16x8 ka = *(const s16x8*)&Ks[b][(grp * 32 + l31) * 128 +
                                              (((2 * s + hi) ^ (lane & 15)) * 8)];
        st[grp] = __builtin_amdgcn_mfma_f32_32x32x16_bf16(ka, qb[s], st[grp], 0, 0, 0);
      }
    __builtin_amdgcn_s_setprio(0);

    // hoist V B-frags (ds_read latency hides under softmax VALU)
    s16x8 vb[4][4];
#pragma unroll
    for (int s = 0; s < 4; ++s)
#pragma unroll
      for (int d = 0; d < 4; ++d)
        vb[s][d] = *(const s16x8*)&Vs[b][(d * 32 + l31) * 64 +
                                         (((2 * s + hi) ^ (lane & 7)) * 8)];

    if (t0 + lt == NTILES - 1) {  // keys 3104+16.. invalid: group1 regs 8..15
#pragma unroll
      for (int r = 8; r < 16; ++r) st[1][r] = NEGBIG;
    }
    // row max (lane-local + 1 partner exchange)
    float rm = st[0][0];
#pragma unroll
    for (int r = 1; r < 16; ++r) rm = fmaxf(rm, st[0][r]);
#pragma unroll
    for (int r = 0; r < 16; ++r) rm = fmaxf(rm, st[1][r]);
    rm = fmaxf(rm, __shfl_xor(rm, 32));

    if (__any(rm > m + THRL2)) {  // deferred rescale
      const float mn = fmaxf(m, rm);
      const float fac = exp2f(m - mn);
      m = mn;
      sl *= fac;
#pragma unroll
      for (int r = 0; r < 16; ++r) {
        const float fq = __shfl(fac, ((r & 3) + 8 * (r >> 2)) + 4 * hi);
#pragma unroll
        for (int d = 0; d < 4; ++d) o[d][r] *= fq;
      }
    }
    // P = exp2(S - m), lane-local sum, pack to bf16 pairs, partner exchange
    unsigned W[16], X[16];
#pragma unroll
    for (int grp = 0; grp < 2; ++grp)
#pragma unroll
      for (int i = 0; i < 8; ++i) {
        const float p0 = exp2f(st[grp][2 * i] - m);
        const float p1 = exp2f(st[grp][2 * i + 1] - m);
        sl += p0 + p1;
        W[grp * 8 + i] = cvtpk(p0, p1);
      }
#pragma unroll
    for (int j = 0; j < 16; ++j) X[j] = __shfl_xor((int)W[j], 32);

    // O += P V
    __builtin_amdgcn_s_setprio(1);
#pragma unroll
    for (int s = 0; s < 4; ++s) {
      const int base = (s >> 1) * 8 + (s & 1) * 4;
      unsigned pw[4];
      pw[0] = hi ? X[base + 2] : W[base + 0];
      pw[1] = hi ? X[base + 3] : W[base + 1];
      pw[2] = hi ? W[base + 2] : X[base + 0];
      pw[3] = hi ? W[base + 3] : X[base + 1];
      const s16x8 pa = *(const s16x8*)pw;
#pragma unroll
      for (int d = 0; d < 4; ++d)
        o[d] = __builtin_amdgcn_mfma_f32_32x32x16_bf16(pa, vb[s][d], o[d], 0, 0, 0);
    }
    __builtin_amdgcn_s_setprio(0);
    __builtin_amdgcn_s_barrier();
    __builtin_amdgcn_sched_barrier(0);
  }

  // partial output: raw o (bf16) + merged (m, sum)
  sl += __shfl_xor(sl, 32);
  if (hi == 0 && qrow < SEQ)
    ms[((size_t)z * HEADS + h) * SPAD + qrow] = make_float2(m, sl);
  u16* Ob = Opart + (((size_t)z * HEADS + h) * SPAD) * HD;
#pragma unroll
  for (int r = 0; r < 16; ++r) {
    const int row = blockIdx.x * 160 + w * 32 + ((r & 3) + 8 * (r >> 2)) + 4 * hi;
    if (row < SEQ) {
#pragma unroll
      for (int d = 0; d < 4; ++d)
        Ob[(size_t)row * HD + d * 32 + l31] = f2bf(o[d][r]);
    }
  }
}

// ---------------- 7b. combine the two KV-half partials ---------------------
// one warp per (h, q) row: AttO[q][h*128+d] = sum_z o_z e^{m_z-M} / sum_z s_z e^{m_z-M}
__global__ __launch_bounds__(256) void k_combine(const u16* __restrict__ Opart,
                                                 const float2* __restrict__ ms,
                                                 u16* __restrict__ AttO) {
  const int rid = blockIdx.x * 4 + (threadIdx.x >> 6);
  if (rid >= HEADS * SEQ) return;
  const int h = rid / SEQ, q = rid - h * SEQ;
  const int lane = threadIdx.x & 63;
  const float2 ms0 = ms[((size_t)0 * HEADS + h) * SPAD + q];
  const float2 ms1 = ms[((size_t)1 * HEADS + h) * SPAD + q];
  const float M = fmaxf(ms0.x, ms1.x);
  const float w0 = exp2f(ms0.x - M), w1 = exp2f(ms1.x - M);
  const float rden = 1.0f / (ms0.y * w0 + ms1.y * w1);
  const unsigned o0 = *(const unsigned*)&Opart[(((size_t)0 * HEADS + h) * SPAD + q) * HD + 2 * lane];
  const unsigned o1 = *(const unsigned*)&Opart[(((size_t)1 * HEADS + h) * SPAD + q) * HD + 2 * lane];
  const float a0 = (bf2f(o0 & 0xffff) * w0 + bf2f(o1 & 0xffff) * w1) * rden;
  const float a1 = (bf2f(o0 >> 16) * w0 + bf2f(o1 >> 16) * w1) * rden;
  *(unsigned*)&AttO[(size_t)q * DIM + h * HD + 2 * lane] =
      (unsigned)f2bf(a0) | ((unsigned)f2bf(a1) << 16);
}

// ---------------------------------------------------------------------------
extern "C" void kernel_launch(void* const* d_in, const int* in_sizes, int n_in,
                              void* d_out, int out_size, void* d_ws, size_t ws_size,
                              hipStream_t stream) {
  const float* x    = (const float*)d_in[0];
  const float* freqs= (const float*)d_in[1];
  const float* Wq   = (const float*)d_in[2];
  const float* bq   = (const float*)d_in[3];
  const float* gq   = (const float*)d_in[4];
  const float* Wk   = (const float*)d_in[5];
  const float* bk   = (const float*)d_in[6];
  const float* gk   = (const float*)d_in[7];
  const float* Wv   = (const float*)d_in[8];
  const float* bv   = (const float*)d_in[9];
  const float* Wo   = (const float*)d_in[10];
  const float* bo   = (const float*)d_in[11];
  const float* qkfb = (const float*)d_in[12];
  const float* vfb  = (const float*)d_in[13];
  const float* vsb  = (const float*)d_in[14];

  if (ws_size < (size_t)87705600) return;

  char* ws = (char*)d_ws;
  u16*   xb    = (u16*)(ws);               // [3200][1536] bf16
  u16*   Vt    = (u16*)(ws);               // alias: xb dead after QKV GEMM
  u16*   WtAll = (u16*)(ws + 9830400);     // [4608][1536] bf16 (Wq|Wk|Wv)^T
  u16*   WoT   = (u16*)(ws + 23986176);    // [1536][1536] bf16 Wo^T
  float* bcat  = (float*)(ws + 28704768);  // [4608]
  u16*   Pqkv  = (u16*)(ws + 28723200);    // [3200][4608] bf16
  u16*   Opart = (u16*)(ws + 28723200);    // alias: 2x12x3200x128 bf16 (19.66MB)
  float2* msP  = (float2*)(ws + 48384000); // 2x12x3200 float2 (614KB)
  u16*   Qf    = (u16*)(ws + 58214400);    // [3200][1536] bf16
  u16*   Kf    = (u16*)(ws + 68044800);    // [3200][1536] bf16
  u16*   Vf    = (u16*)(ws + 77875200);    // [3200][1536] bf16
  u16*   AttO  = (u16*)(ws + 77875200);    // alias: Vf dead after transpose_v

  k_convert_x<<<4800, 256, 0, stream>>>(x, xb);
  k_transpose_w<<<dim3(48, 48, 4), 256, 0, stream>>>(Wq, Wk, Wv, Wo, WtAll, WoT);
  k_biascat<<<18, 256, 0, stream>>>(bq, bk, bv, bcat);
  k_gemm<1><<<dim3(36, 25), 256, 0, stream>>>(xb, WtAll, bcat, Pqkv, NQKV, DIM, SPAD);
  k_post<<<SEQ, 256, 0, stream>>>(Pqkv, freqs, gq, gk, qkfb, vfb, vsb, Qf, Kf, Vf);
  k_transpose_v<<<dim3(50, 24), 256, 0, stream>>>(Vf, Vt);
  k_attn<<<dim3(20, 12, 2), 320, 0, stream>>>(Qf, Kf, Vt, Opart, msP);
  k_combine<<<9360, 256, 0, stream>>>(Opart, msP, AttO);
  k_gemm<0><<<dim3(12, 25), 256, 0, stream>>>(AttO, WoT, bo, d_out, DIM, DIM, SEQ);
}